// Round 6
// baseline (1435.677 us; speedup 1.0000x reference)
//
#include <hip/hip_runtime.h>
#include <cstdint>
#include <cstddef>

// Problem shape (fixed by the reference): B=8, C=192, Tx=512, Ty=2048.
#define BB 8
#define CC 192
#define TXX 512
#define TYY 2048

#define NEG_INF (-1e9f)
#define HALF_LOG_2PI 0.9189385332046727f  // 0.5*log(2*pi)

// ---- output layout (floats, concatenated in return order) ----
// out0: MAS_path [B,1,Ty,Tx]  = 8*2048*512 = 8388608
// out1: m_p_a    [B,C,Ty]     = 3145728
// out2: logs_p_a [B,C,Ty]     = 3145728
// out3: loss_kl  scalar       = 1
// out4: duration [B,1,Tx]     = 4096
#define O1 8388608
#define O2 11534336
#define O3 14680064
#define O4 14680065

// ---- workspace layout (bytes). total ~39.1 MB ----
#define WS_NEG   0           // neg_cent fp32 [B,Ty,Tx]           33,554,432 B
#define WS_S     33554432    // s_p_sq_r [B,C,Tx]                  3,145,728 B
#define WS_MSR   36700160    // m_p * s  [B,C,Tx]                  3,145,728 B
#define WS_BIAS  39845888    // nc1+nc4  [B,Tx]                       16,384 B
#define WS_DIRS  39862272    // dir bits [B,Ty,64] bytes           1,048,576 B
#define WS_IDX   40910848    // idx_map  [B,Ty] int                   65,536 B
#define WS_LENS  40976384    // int text_len[8], spec_len[8]             64 B
#define WS_PART  40976448    // kl partials [3072] float              12,288 B

// Builtin vector type: unlike HIP's float4 class, clang ext_vector_type is a
// first-class type -> volatile loads are legal and lower to ONE
// global_load_dwordx4 (not split, not reorderable vs other volatiles).
typedef float vfloat4 __attribute__((ext_vector_type(4)));

// ---------------------------------------------------------------------------
// Zero the path output region (mostly-zero one-hot) + duration.
__global__ void k_zero(float* __restrict__ out) {
    int64_t i = (int64_t)blockIdx.x * blockDim.x + threadIdx.x;
    const int64_t n4 = (int64_t)BB * TYY * TXX / 4;
    float4 z4 = make_float4(0.f, 0.f, 0.f, 0.f);
    float4* p4 = (float4*)out;
    for (int64_t k = i; k < n4; k += (int64_t)gridDim.x * blockDim.x) p4[k] = z4;
    if (i < BB * TXX) out[O4 + i] = 0.0f;
}

// s = exp(-2*logs_p), msr = m_p * s   (elementwise over [B,C,Tx])
__global__ void k_prep(const float* __restrict__ logs_p, const float* __restrict__ m_p,
                       float* __restrict__ s, float* __restrict__ msr) {
    int i = blockIdx.x * blockDim.x + threadIdx.x;  // exactly B*C*Tx threads
    float lp = logs_p[i], m = m_p[i];
    float sv = expf(-2.0f * lp);
    s[i] = sv;
    msr[i] = m * sv;
}

// bias[b,x] = sum_c( -0.5*log(2pi) - logs_p - 0.5*m_p*msr )   (nc1 + nc4)
__global__ void k_bias(const float* __restrict__ logs_p, const float* __restrict__ m_p,
                       const float* __restrict__ msr, float* __restrict__ bias) {
    int i = blockIdx.x * blockDim.x + threadIdx.x;  // B*Tx = 4096 threads
    int b = i >> 9, x = i & (TXX - 1);
    size_t base = (size_t)b * CC * TXX + x;
    const float* lpb = logs_p + base;
    const float* mb  = m_p + base;
    const float* msb = msr + base;
    float acc = 0.f;
#pragma unroll 8
    for (int c = 0; c < CC; ++c)
        acc += -HALF_LOG_2PI - lpb[(size_t)c * TXX] - 0.5f * mb[(size_t)c * TXX] * msb[(size_t)c * TXX];
    bias[i] = acc;
}

// text_len / spec_len per batch from the float masks.
__global__ void k_len(const float* __restrict__ tmask, const float* __restrict__ smask,
                      int* __restrict__ lens) {
    __shared__ float red[256];
    int b = blockIdx.x, tid = threadIdx.x;
    float ts = 0.f;
    for (int i = tid; i < TXX; i += 256) ts += tmask[b * TXX + i];
    red[tid] = ts; __syncthreads();
    for (int s = 128; s > 0; s >>= 1) { if (tid < s) red[tid] += red[tid + s]; __syncthreads(); }
    if (tid == 0) lens[b] = (int)(red[0] + 0.5f);
    __syncthreads();
    float ss = 0.f;
    for (int i = tid; i < TYY; i += 256) ss += smask[b * TYY + i];
    red[tid] = ss; __syncthreads();
    for (int s = 128; s > 0; s >>= 1) { if (tid < s) red[tid] += red[tid + s]; __syncthreads(); }
    if (tid == 0) lens[8 + b] = (int)(red[0] + 0.5f);
}

// neg_cent[b,t,x] = bias[b,x] + sum_c( z*msr + (-0.5*z^2)*s )
// fp32 LDS-tiled GEMM: 64x64 tile, BK=16, 256 threads, 4x4 per thread.
__global__ __launch_bounds__(256) void k_gemm(const float* __restrict__ z,
                                              const float* __restrict__ msr,
                                              const float* __restrict__ sarr,
                                              const float* __restrict__ bias,
                                              float* __restrict__ neg) {
    __shared__ float Zs[16][68], Ms[16][68], Ss[16][68];  // +4 pad
    int tid = threadIdx.x;
    int tx = tid & 15, ty = tid >> 4;          // cols (x), rows (t)
    int x0 = blockIdx.x * 64, t0 = blockIdx.y * 64, b = blockIdx.z;
    const float* zb = z    + (size_t)b * CC * TYY;
    const float* mb = msr  + (size_t)b * CC * TXX;
    const float* sb = sarr + (size_t)b * CC * TXX;
    int lr = tid >> 4, lc = (tid & 15) * 4;    // staging: row(k), col*4
    float acc[4][4] = {};
    for (int k0 = 0; k0 < CC; k0 += 16) {
        float4 zv = *(const float4*)(zb + (size_t)(k0 + lr) * TYY + t0 + lc);
        float4 mv = *(const float4*)(mb + (size_t)(k0 + lr) * TXX + x0 + lc);
        float4 sv = *(const float4*)(sb + (size_t)(k0 + lr) * TXX + x0 + lc);
        __syncthreads();
        *(float4*)&Zs[lr][lc] = zv;
        *(float4*)&Ms[lr][lc] = mv;
        *(float4*)&Ss[lr][lc] = sv;
        __syncthreads();
#pragma unroll
        for (int k = 0; k < 16; ++k) {
            float4 a4  = *(const float4*)&Zs[k][ty * 4];
            float4 bm4 = *(const float4*)&Ms[k][tx * 4];
            float4 bs4 = *(const float4*)&Ss[k][tx * 4];
            float av[4]  = {a4.x, a4.y, a4.z, a4.w};
            float bmv[4] = {bm4.x, bm4.y, bm4.z, bm4.w};
            float bsv[4] = {bs4.x, bs4.y, bs4.z, bs4.w};
#pragma unroll
            for (int i2 = 0; i2 < 4; ++i2) {
                float a2 = -0.5f * av[i2] * av[i2];
#pragma unroll
                for (int j = 0; j < 4; ++j)
                    acc[i2][j] += av[i2] * bmv[j] + a2 * bsv[j];
            }
        }
    }
    float4 b4 = *(const float4*)(bias + b * TXX + x0 + tx * 4);
    float bv[4] = {b4.x, b4.y, b4.z, b4.w};
#pragma unroll
    for (int i2 = 0; i2 < 4; ++i2) {
        int t = t0 + ty * 4 + i2;
        float4 o;
        o.x = acc[i2][0] + bv[0]; o.y = acc[i2][1] + bv[1];
        o.z = acc[i2][2] + bv[2]; o.w = acc[i2][3] + bv[3];
        *(float4*)(neg + ((size_t)b * TYY + t) * TXX + x0 + tx * 4) = o;
    }
}

// Monotonic alignment search: forward DP + backtrack, one wave per batch.
// Forward: lane L owns x in [8L, 8L+8); all x independent given prev row;
// one shfl_up per row for the lane boundary.
// R2/R3 post-mortem: the compiler's pressure-driven scheduler sank
// source-level prefetch loads back to their uses (564 us = one HBM latency
// per row), regardless of launch bounds. R4 asm-tied operands: unsupported.
// R5 volatile float4: HIP float4 is a class, no volatile operator=.
// R6: volatile loads of clang ext_vector_type(4) (builtin type, legal
// volatile, single dwordx4). Volatile vmem ops cannot be reordered relative
// to each other, so load(y+16) cannot sink past load(y+17): the 16-row
// pipeline depth is structural. SIInsertWaitcnts emits fine-grained
// vmcnt(N) from its per-register scoreboard.
// Direction bits (diag > value) packed 8/lane -> dirs[b][y][lane] byte.
// Backtrack: per 64-row slab, lane j caches a 4-word column window of row
// (y0-j)'s bits; the serial chain fetches via __shfl (lane index is the loop
// counter, so the shfl is not on the data-dependent chain).
#define PF 16
__global__ __launch_bounds__(64, 1) void k_mas(const float* __restrict__ neg,
                                               const int* __restrict__ lens,
                                               uint8_t* __restrict__ dirs,
                                               int* __restrict__ idx_map) {
    int b = blockIdx.x, lane = threadIdx.x;
    const float* nc = neg + (size_t)b * TYY * TXX;
    uint8_t* db = dirs + (size_t)b * TYY * 64;
    int tlen = lens[b], slen = lens[8 + b];

    // ---- forward ----
    float v[8];
    {
        const volatile vfloat4* rp = (const volatile vfloat4*)nc + lane * 2;
        vfloat4 r0 = rp[0];
#pragma unroll
        for (int j = 0; j < 8; ++j) v[j] = NEG_INF;
        if (lane == 0) v[0] = r0.x;   // y==0: only x==0 gets its score
        db[lane] = 0;                 // dirs row 0 is all-false
    }
    // volatile prefetch ring: slot p holds row (1+p), refilled PF rows ahead.
    vfloat4 pb0[PF], pb1[PF];
#pragma unroll
    for (int p = 0; p < PF; ++p) {
        const volatile vfloat4* rp =
            (const volatile vfloat4*)(nc + (size_t)(1 + p) * TXX) + lane * 2;
        pb0[p] = rp[0];
        pb1[p] = rp[1];
    }
    for (int y0 = 1; y0 < TYY; y0 += PF) {
#pragma unroll
        for (int j = 0; j < PF; ++j) {
            int y = y0 + j;
            if (y < TYY) {
                vfloat4 c0 = pb0[j], c1 = pb1[j];
                int yn = y + PF;
                if (yn < TYY) {
                    const volatile vfloat4* rp =
                        (const volatile vfloat4*)(nc + (size_t)yn * TXX) + lane * 2;
                    pb0[j] = rp[0];
                    pb1[j] = rp[1];
                }
                float sc[8] = {c0.x, c0.y, c0.z, c0.w, c1.x, c1.y, c1.z, c1.w};
                float pl = __shfl_up(v[7], 1);
                if (lane == 0) pl = NEG_INF;
                float nv[8];
                unsigned d = 0;
#pragma unroll
                for (int jj = 0; jj < 8; ++jj) {
                    float diag = (jj == 0) ? pl : v[jj - 1];
                    if (diag > v[jj]) d |= (1u << jj);
                    nv[jj] = sc[jj] + fmaxf(v[jj], diag);
                }
#pragma unroll
                for (int jj = 0; jj < 8; ++jj) v[jj] = nv[jj];
                db[(size_t)y * 64 + lane] = (uint8_t)d;
            }
        }
    }

    // ---- backtrack ----
    int idx = tlen - 1;
    int y0 = slen - 1;
    while (y0 >= 0) {
        int y = y0 - lane;
        int yy = (y < 0) ? 0 : y;
        // 4-word window [w0, w0+3] covers idx range for the whole slab
        // (idx decreases by at most 64 across 64 steps).
        int w0 = (idx >> 5) - 2;
        if (w0 < 0) w0 = 0;
        if (w0 > 12) w0 = 12;
        const uint32_t* rw = (const uint32_t*)(db + (size_t)yy * 64);
        uint32_t wa = rw[w0], wbv = rw[w0 + 1], wcv = rw[w0 + 2], wdv = rw[w0 + 3];
        int nsteps = (y0 + 1 < 64) ? y0 + 1 : 64;
        int cap = 0;
        for (int j = 0; j < nsteps; ++j) {
            if (lane == j) cap = idx;   // row y0-j emits one-hot at entering idx
            uint32_t s0 = (uint32_t)__shfl((int)wa,  j);
            uint32_t s1 = (uint32_t)__shfl((int)wbv, j);
            uint32_t s2 = (uint32_t)__shfl((int)wcv, j);
            uint32_t s3 = (uint32_t)__shfl((int)wdv, j);
            int wi = (idx >> 5) - w0;   // 0..3 guaranteed
            uint32_t lo = (wi & 1) ? s1 : s0;
            uint32_t hi = (wi & 1) ? s3 : s2;
            uint32_t word = (wi & 2) ? hi : lo;
            int bit = (int)((word >> (idx & 31)) & 1u);
            int yj = y0 - j;
            int move = (int)(idx != 0) & ((int)(idx == yj) | bit);
            idx -= move;
        }
        if (lane < nsteps) idx_map[b * TYY + y] = cap;
        y0 -= 64;
    }
}

// Scatter path one-hots + duration histogram from idx_map.
__global__ void k_scatter(const int* __restrict__ lens, const int* __restrict__ idx_map,
                          float* __restrict__ out) {
    int i = blockIdx.x * blockDim.x + threadIdx.x;  // B*Ty threads
    int b = i >> 11, y = i & (TYY - 1);
    if (y < lens[8 + b]) {
        int x = idx_map[i];
        out[(size_t)i * TXX + x] = 1.0f;
        atomicAdd(&out[O4 + b * TXX + x], 1.0f);
    }
}

// Gather m_p/logs_p onto spec frames via idx_map; fused KL partial sums.
__global__ __launch_bounds__(256) void k_gather(const float* __restrict__ z_p,
                                                const float* __restrict__ m_p,
                                                const float* __restrict__ logs_p,
                                                const float* __restrict__ logs_q,
                                                const int* __restrict__ lens,
                                                const int* __restrict__ idx_map,
                                                float* __restrict__ out,
                                                float* __restrict__ partials) {
    const int S = BB * CC * TYY / 4;  // 786432 stride, 4 elems/thread
    int base = blockIdx.x * 256 + threadIdx.x;
    float klsum = 0.f;
#pragma unroll
    for (int r = 0; r < 4; ++r) {
        int i = base + r * S;
        int t = i & (TYY - 1);
        int bc = i >> 11;      // b*C + c
        int b = bc / CC;
        float ma = 0.f, la = 0.f;
        if (t < lens[8 + b]) {
            int x = idx_map[b * TYY + t];
            size_t off = (size_t)bc * TXX + x;
            ma = m_p[off];
            la = logs_p[off];
            float zv = z_p[i], lq = logs_q[i];
            float dz = zv - ma;
            klsum += la - lq - 0.5f + 0.5f * dz * dz * expf(-2.0f * la);
        }
        out[O1 + i] = ma;
        out[O2 + i] = la;
    }
    for (int o = 32; o > 0; o >>= 1) klsum += __shfl_down(klsum, o);
    __shared__ float red[4];
    if ((threadIdx.x & 63) == 0) red[threadIdx.x >> 6] = klsum;
    __syncthreads();
    if (threadIdx.x == 0) partials[blockIdx.x] = red[0] + red[1] + red[2] + red[3];
}

__global__ void k_final(const float* __restrict__ partials, const int* __restrict__ lens,
                        float* __restrict__ out) {
    float s = 0.f;
    for (int i = threadIdx.x; i < 3072; i += 256) s += partials[i];
    for (int o = 32; o > 0; o >>= 1) s += __shfl_down(s, o);
    __shared__ float red[4];
    if ((threadIdx.x & 63) == 0) red[threadIdx.x >> 6] = s;
    __syncthreads();
    if (threadIdx.x == 0) {
        float tot = 0.f;
        for (int b = 0; b < 8; ++b) tot += (float)lens[8 + b];
        out[O3] = (red[0] + red[1] + red[2] + red[3]) / tot;
    }
}

extern "C" void kernel_launch(void* const* d_in, const int* in_sizes, int n_in,
                              void* d_out, int out_size, void* d_ws, size_t ws_size,
                              hipStream_t stream) {
    const float* z_p    = (const float*)d_in[0];
    const float* m_p    = (const float*)d_in[1];
    const float* logs_p = (const float*)d_in[2];
    const float* logs_q = (const float*)d_in[3];
    const float* tmask  = (const float*)d_in[4];
    const float* smask  = (const float*)d_in[5];
    float* out = (float*)d_out;
    char* ws = (char*)d_ws;

    float*   neg      = (float*)(ws + WS_NEG);
    float*   sarr     = (float*)(ws + WS_S);
    float*   msr      = (float*)(ws + WS_MSR);
    float*   bias     = (float*)(ws + WS_BIAS);
    uint8_t* dirs     = (uint8_t*)(ws + WS_DIRS);
    int*     idx_map  = (int*)(ws + WS_IDX);
    int*     lens     = (int*)(ws + WS_LENS);
    float*   partials = (float*)(ws + WS_PART);

    hipLaunchKernelGGL(k_zero,    dim3(2048),      dim3(256), 0, stream, out);
    hipLaunchKernelGGL(k_prep,    dim3(3072),      dim3(256), 0, stream, logs_p, m_p, sarr, msr);
    hipLaunchKernelGGL(k_bias,    dim3(16),        dim3(256), 0, stream, logs_p, m_p, msr, bias);
    hipLaunchKernelGGL(k_len,     dim3(8),         dim3(256), 0, stream, tmask, smask, lens);
    hipLaunchKernelGGL(k_gemm,    dim3(8, 32, 8),  dim3(256), 0, stream, z_p, msr, sarr, bias, neg);
    hipLaunchKernelGGL(k_mas,     dim3(8),         dim3(64),  0, stream, neg, lens, dirs, idx_map);
    hipLaunchKernelGGL(k_scatter, dim3(64),        dim3(256), 0, stream, lens, idx_map, out);
    hipLaunchKernelGGL(k_gather,  dim3(3072),      dim3(256), 0, stream, z_p, m_p, logs_p, logs_q,
                       lens, idx_map, out, partials);
    hipLaunchKernelGGL(k_final,   dim3(1),         dim3(256), 0, stream, partials, lens, out);
}

// Round 7
// 737.818 us; speedup vs baseline: 1.9458x; 1.9458x over previous
//
#include <hip/hip_runtime.h>
#include <cstdint>
#include <cstddef>

// Problem shape (fixed by the reference): B=8, C=192, Tx=512, Ty=2048.
#define BB 8
#define CC 192
#define TXX 512
#define TYY 2048

#define NEG_INF (-1e9f)
#define HALF_LOG_2PI 0.9189385332046727f  // 0.5*log(2*pi)

// ---- output layout (floats, concatenated in return order) ----
// out0: MAS_path [B,1,Ty,Tx]  = 8*2048*512 = 8388608
// out1: m_p_a    [B,C,Ty]     = 3145728
// out2: logs_p_a [B,C,Ty]     = 3145728
// out3: loss_kl  scalar       = 1
// out4: duration [B,1,Tx]     = 4096
#define O1 8388608
#define O2 11534336
#define O3 14680064
#define O4 14680065

// ---- workspace layout (bytes). total ~39.1 MB ----
#define WS_NEG   0           // neg_cent fp32 [B,Ty,Tx]           33,554,432 B
#define WS_S     33554432    // s_p_sq_r [B,C,Tx]                  3,145,728 B
#define WS_MSR   36700160    // m_p * s  [B,C,Tx]                  3,145,728 B
#define WS_BIAS  39845888    // nc1+nc4  [B,Tx]                       16,384 B
#define WS_DIRS  39862272    // dir bits [B,Ty,64] bytes           1,048,576 B
#define WS_IDX   40910848    // idx_map  [B,Ty] int                   65,536 B
#define WS_LENS  40976384    // int text_len[8], spec_len[8]             64 B
#define WS_PART  40976448    // kl partials [3072] float              12,288 B

// ---------------------------------------------------------------------------
// Zero the path output region (mostly-zero one-hot) + duration.
__global__ void k_zero(float* __restrict__ out) {
    int64_t i = (int64_t)blockIdx.x * blockDim.x + threadIdx.x;
    const int64_t n4 = (int64_t)BB * TYY * TXX / 4;
    float4 z4 = make_float4(0.f, 0.f, 0.f, 0.f);
    float4* p4 = (float4*)out;
    for (int64_t k = i; k < n4; k += (int64_t)gridDim.x * blockDim.x) p4[k] = z4;
    if (i < BB * TXX) out[O4 + i] = 0.0f;
}

// s = exp(-2*logs_p), msr = m_p * s   (elementwise over [B,C,Tx])
__global__ void k_prep(const float* __restrict__ logs_p, const float* __restrict__ m_p,
                       float* __restrict__ s, float* __restrict__ msr) {
    int i = blockIdx.x * blockDim.x + threadIdx.x;  // exactly B*C*Tx threads
    float lp = logs_p[i], m = m_p[i];
    float sv = expf(-2.0f * lp);
    s[i] = sv;
    msr[i] = m * sv;
}

// bias[b,x] = sum_c( -0.5*log(2pi) - logs_p - 0.5*m_p*msr )   (nc1 + nc4)
__global__ void k_bias(const float* __restrict__ logs_p, const float* __restrict__ m_p,
                       const float* __restrict__ msr, float* __restrict__ bias) {
    int i = blockIdx.x * blockDim.x + threadIdx.x;  // B*Tx = 4096 threads
    int b = i >> 9, x = i & (TXX - 1);
    size_t base = (size_t)b * CC * TXX + x;
    const float* lpb = logs_p + base;
    const float* mb  = m_p + base;
    const float* msb = msr + base;
    float acc = 0.f;
#pragma unroll 8
    for (int c = 0; c < CC; ++c)
        acc += -HALF_LOG_2PI - lpb[(size_t)c * TXX] - 0.5f * mb[(size_t)c * TXX] * msb[(size_t)c * TXX];
    bias[i] = acc;
}

// text_len / spec_len per batch from the float masks.
__global__ void k_len(const float* __restrict__ tmask, const float* __restrict__ smask,
                      int* __restrict__ lens) {
    __shared__ float red[256];
    int b = blockIdx.x, tid = threadIdx.x;
    float ts = 0.f;
    for (int i = tid; i < TXX; i += 256) ts += tmask[b * TXX + i];
    red[tid] = ts; __syncthreads();
    for (int s = 128; s > 0; s >>= 1) { if (tid < s) red[tid] += red[tid + s]; __syncthreads(); }
    if (tid == 0) lens[b] = (int)(red[0] + 0.5f);
    __syncthreads();
    float ss = 0.f;
    for (int i = tid; i < TYY; i += 256) ss += smask[b * TYY + i];
    red[tid] = ss; __syncthreads();
    for (int s = 128; s > 0; s >>= 1) { if (tid < s) red[tid] += red[tid + s]; __syncthreads(); }
    if (tid == 0) lens[8 + b] = (int)(red[0] + 0.5f);
}

// neg_cent[b,t,x] = bias[b,x] + sum_c( z*msr + (-0.5*z^2)*s )
// fp32 LDS-tiled GEMM: 64x64 tile, BK=16, 256 threads, 4x4 per thread.
__global__ __launch_bounds__(256) void k_gemm(const float* __restrict__ z,
                                              const float* __restrict__ msr,
                                              const float* __restrict__ sarr,
                                              const float* __restrict__ bias,
                                              float* __restrict__ neg) {
    __shared__ float Zs[16][68], Ms[16][68], Ss[16][68];  // +4 pad
    int tid = threadIdx.x;
    int tx = tid & 15, ty = tid >> 4;          // cols (x), rows (t)
    int x0 = blockIdx.x * 64, t0 = blockIdx.y * 64, b = blockIdx.z;
    const float* zb = z    + (size_t)b * CC * TYY;
    const float* mb = msr  + (size_t)b * CC * TXX;
    const float* sb = sarr + (size_t)b * CC * TXX;
    int lr = tid >> 4, lc = (tid & 15) * 4;    // staging: row(k), col*4
    float acc[4][4] = {};
    for (int k0 = 0; k0 < CC; k0 += 16) {
        float4 zv = *(const float4*)(zb + (size_t)(k0 + lr) * TYY + t0 + lc);
        float4 mv = *(const float4*)(mb + (size_t)(k0 + lr) * TXX + x0 + lc);
        float4 sv = *(const float4*)(sb + (size_t)(k0 + lr) * TXX + x0 + lc);
        __syncthreads();
        *(float4*)&Zs[lr][lc] = zv;
        *(float4*)&Ms[lr][lc] = mv;
        *(float4*)&Ss[lr][lc] = sv;
        __syncthreads();
#pragma unroll
        for (int k = 0; k < 16; ++k) {
            float4 a4  = *(const float4*)&Zs[k][ty * 4];
            float4 bm4 = *(const float4*)&Ms[k][tx * 4];
            float4 bs4 = *(const float4*)&Ss[k][tx * 4];
            float av[4]  = {a4.x, a4.y, a4.z, a4.w};
            float bmv[4] = {bm4.x, bm4.y, bm4.z, bm4.w};
            float bsv[4] = {bs4.x, bs4.y, bs4.z, bs4.w};
#pragma unroll
            for (int i2 = 0; i2 < 4; ++i2) {
                float a2 = -0.5f * av[i2] * av[i2];
#pragma unroll
                for (int j = 0; j < 4; ++j)
                    acc[i2][j] += av[i2] * bmv[j] + a2 * bsv[j];
            }
        }
    }
    float4 b4 = *(const float4*)(bias + b * TXX + x0 + tx * 4);
    float bv[4] = {b4.x, b4.y, b4.z, b4.w};
#pragma unroll
    for (int i2 = 0; i2 < 4; ++i2) {
        int t = t0 + ty * 4 + i2;
        float4 o;
        o.x = acc[i2][0] + bv[0]; o.y = acc[i2][1] + bv[1];
        o.z = acc[i2][2] + bv[2]; o.w = acc[i2][3] + bv[3];
        *(float4*)(neg + ((size_t)b * TYY + t) * TXX + x0 + tx * 4) = o;
    }
}

// Monotonic alignment search, producer-consumer wave specialization.
// R2/R3: scheduler sinks register prefetch (1 HBM latency/row). R4: tied
// asm operands unsupported. R6: volatile loads get vmcnt(0) EACH (2x worse).
// R7: pipeline across WAVES, which no compiler pass can collapse.
//   wave 0          = DP consumer, reads scores only from LDS.
//   waves 1..3      = feeders; feeder w stages groups g≡w-1 (mod 3), where a
//                     group = 8 rows, into a 4-slot LDS ring (64 KB). Each
//                     feeder thread: 16 independent dwordx4 loads then 32 LDS
//                     stores — the memcpy pattern the scheduler pipelines.
// Sync: volatile LDS counters (feed_done[3], cons_cnt) + threadfence_block.
// LDS row layout is half-split (even float4s at pos 0..63, odd at 64..127):
// consumer lane L reads pos L and 64+L (stride-16B, conflict-free) and gets
// exactly floats 8L..8L+7, so the DP math is unchanged from R1.
// Backtrack: per 64-row slab, lane j caches a 4-word column window of row
// (y0-j)'s dir bits; serial chain fetches via __shfl (lane idx = loop
// counter, not on the dependent chain).
__global__ __launch_bounds__(256, 1) void k_mas(const float* __restrict__ neg,
                                                const int* __restrict__ lens,
                                                uint8_t* __restrict__ dirs,
                                                int* __restrict__ idx_map) {
    __shared__ float4 ring[4096];   // 4 slots x 8 rows x 128 float4 = 64 KB
    __shared__ int feed_done[3];
    __shared__ int cons_cnt;

    int b = blockIdx.x;
    int tid = threadIdx.x;
    int wave = tid >> 6, lane = tid & 63;
    const float* nc = neg + (size_t)b * TYY * TXX;
    uint8_t* db = dirs + (size_t)b * TYY * 64;

    if (tid == 0) { feed_done[0] = feed_done[1] = feed_done[2] = 0; cons_cnt = 0; }
    __syncthreads();

    if (wave != 0) {
        // ---- feeder ----
        int w = wave - 1;  // 0..2
        const float4* nc4 = (const float4*)nc;
        int cnt = 0;
        for (int g = w; g < TYY / 8; g += 3) {
            if (g >= 4) {
                while (*(volatile int*)&cons_cnt < g - 3) __builtin_amdgcn_s_sleep(1);
            }
            const float4* g4 = nc4 + (size_t)g * 1024;  // 8 rows x 128 float4
            float4 t[16];
#pragma unroll
            for (int r = 0; r < 8; ++r) {
                t[2 * r]     = g4[r * 128 + lane];
                t[2 * r + 1] = g4[r * 128 + 64 + lane];
            }
            float4* lb = ring + (size_t)(g & 3) * 1024;
            int p0 = (lane & 1) * 64 + (lane >> 1);        // pos of float4 #lane
            int p1 = p0 + 32;                              // pos of float4 #(64+lane)
#pragma unroll
            for (int r = 0; r < 8; ++r) {
                lb[r * 128 + p0] = t[2 * r];
                lb[r * 128 + p1] = t[2 * r + 1];
            }
            __threadfence_block();   // data visible before counter
            ++cnt;
            if (lane == 0) *(volatile int*)&feed_done[w] = cnt;
        }
        return;
    }

    // ---- consumer: forward DP ----
    int tlen = lens[b], slen = lens[8 + b];
    float v[8];
#pragma unroll
    for (int j = 0; j < 8; ++j) v[j] = NEG_INF;

    for (int g = 0; g < TYY / 8; ++g) {
        int f = g % 3, need = g / 3 + 1;
        while (*(volatile int*)&feed_done[f] < need) __builtin_amdgcn_s_sleep(1);
        __threadfence_block();
        const float4* lb = ring + (size_t)(g & 3) * 1024;
        float4 c0 = lb[lane], c1 = lb[64 + lane];
#pragma unroll
        for (int r = 0; r < 8; ++r) {
            float4 n0, n1;
            if (r < 7) { n0 = lb[(r + 1) * 128 + lane]; n1 = lb[(r + 1) * 128 + 64 + lane]; }
            int y = 8 * g + r;
            if (y == 0) {
                if (lane == 0) v[0] = c0.x;   // y==0: only x==0 gets its score
                db[lane] = 0;                 // dirs row 0 all-false
            } else {
                float sc[8] = {c0.x, c0.y, c0.z, c0.w, c1.x, c1.y, c1.z, c1.w};
                float pl = __shfl_up(v[7], 1);
                if (lane == 0) pl = NEG_INF;
                float nv[8];
                unsigned d = 0;
#pragma unroll
                for (int jj = 0; jj < 8; ++jj) {
                    float diag = (jj == 0) ? pl : v[jj - 1];
                    if (diag > v[jj]) d |= (1u << jj);
                    nv[jj] = sc[jj] + fmaxf(v[jj], diag);
                }
#pragma unroll
                for (int jj = 0; jj < 8; ++jj) v[jj] = nv[jj];
                db[(size_t)y * 64 + lane] = (uint8_t)d;
            }
            c0 = n0; c1 = n1;
        }
        __threadfence_block();   // LDS reads done before freeing the slot
        if (lane == 0) *(volatile int*)&cons_cnt = g + 1;
    }

    // ---- backtrack ----
    int idx = tlen - 1;
    int y0 = slen - 1;
    while (y0 >= 0) {
        int y = y0 - lane;
        int yy = (y < 0) ? 0 : y;
        // 4-word window [w0, w0+3] covers idx range for the whole slab
        // (idx decreases by at most 64 across 64 steps).
        int w0 = (idx >> 5) - 2;
        if (w0 < 0) w0 = 0;
        if (w0 > 12) w0 = 12;
        const uint32_t* rw = (const uint32_t*)(db + (size_t)yy * 64);
        uint32_t wa = rw[w0], wbv = rw[w0 + 1], wcv = rw[w0 + 2], wdv = rw[w0 + 3];
        int nsteps = (y0 + 1 < 64) ? y0 + 1 : 64;
        int cap = 0;
        for (int j = 0; j < nsteps; ++j) {
            if (lane == j) cap = idx;   // row y0-j emits one-hot at entering idx
            uint32_t s0 = (uint32_t)__shfl((int)wa,  j);
            uint32_t s1 = (uint32_t)__shfl((int)wbv, j);
            uint32_t s2 = (uint32_t)__shfl((int)wcv, j);
            uint32_t s3 = (uint32_t)__shfl((int)wdv, j);
            int wi = (idx >> 5) - w0;   // 0..3 guaranteed
            uint32_t lo = (wi & 1) ? s1 : s0;
            uint32_t hi = (wi & 1) ? s3 : s2;
            uint32_t word = (wi & 2) ? hi : lo;
            int bit = (int)((word >> (idx & 31)) & 1u);
            int yj = y0 - j;
            int move = (int)(idx != 0) & ((int)(idx == yj) | bit);
            idx -= move;
        }
        if (lane < nsteps) idx_map[b * TYY + y] = cap;
        y0 -= 64;
    }
}

// Scatter path one-hots + duration histogram from idx_map.
__global__ void k_scatter(const int* __restrict__ lens, const int* __restrict__ idx_map,
                          float* __restrict__ out) {
    int i = blockIdx.x * blockDim.x + threadIdx.x;  // B*Ty threads
    int b = i >> 11, y = i & (TYY - 1);
    if (y < lens[8 + b]) {
        int x = idx_map[i];
        out[(size_t)i * TXX + x] = 1.0f;
        atomicAdd(&out[O4 + b * TXX + x], 1.0f);
    }
}

// Gather m_p/logs_p onto spec frames via idx_map; fused KL partial sums.
__global__ __launch_bounds__(256) void k_gather(const float* __restrict__ z_p,
                                                const float* __restrict__ m_p,
                                                const float* __restrict__ logs_p,
                                                const float* __restrict__ logs_q,
                                                const int* __restrict__ lens,
                                                const int* __restrict__ idx_map,
                                                float* __restrict__ out,
                                                float* __restrict__ partials) {
    const int S = BB * CC * TYY / 4;  // 786432 stride, 4 elems/thread
    int base = blockIdx.x * 256 + threadIdx.x;
    float klsum = 0.f;
#pragma unroll
    for (int r = 0; r < 4; ++r) {
        int i = base + r * S;
        int t = i & (TYY - 1);
        int bc = i >> 11;      // b*C + c
        int b = bc / CC;
        float ma = 0.f, la = 0.f;
        if (t < lens[8 + b]) {
            int x = idx_map[b * TYY + t];
            size_t off = (size_t)bc * TXX + x;
            ma = m_p[off];
            la = logs_p[off];
            float zv = z_p[i], lq = logs_q[i];
            float dz = zv - ma;
            klsum += la - lq - 0.5f + 0.5f * dz * dz * expf(-2.0f * la);
        }
        out[O1 + i] = ma;
        out[O2 + i] = la;
    }
    for (int o = 32; o > 0; o >>= 1) klsum += __shfl_down(klsum, o);
    __shared__ float red[4];
    if ((threadIdx.x & 63) == 0) red[threadIdx.x >> 6] = klsum;
    __syncthreads();
    if (threadIdx.x == 0) partials[blockIdx.x] = red[0] + red[1] + red[2] + red[3];
}

__global__ void k_final(const float* __restrict__ partials, const int* __restrict__ lens,
                        float* __restrict__ out) {
    float s = 0.f;
    for (int i = threadIdx.x; i < 3072; i += 256) s += partials[i];
    for (int o = 32; o > 0; o >>= 1) s += __shfl_down(s, o);
    __shared__ float red[4];
    if ((threadIdx.x & 63) == 0) red[threadIdx.x >> 6] = s;
    __syncthreads();
    if (threadIdx.x == 0) {
        float tot = 0.f;
        for (int b = 0; b < 8; ++b) tot += (float)lens[8 + b];
        out[O3] = (red[0] + red[1] + red[2] + red[3]) / tot;
    }
}

extern "C" void kernel_launch(void* const* d_in, const int* in_sizes, int n_in,
                              void* d_out, int out_size, void* d_ws, size_t ws_size,
                              hipStream_t stream) {
    const float* z_p    = (const float*)d_in[0];
    const float* m_p    = (const float*)d_in[1];
    const float* logs_p = (const float*)d_in[2];
    const float* logs_q = (const float*)d_in[3];
    const float* tmask  = (const float*)d_in[4];
    const float* smask  = (const float*)d_in[5];
    float* out = (float*)d_out;
    char* ws = (char*)d_ws;

    float*   neg      = (float*)(ws + WS_NEG);
    float*   sarr     = (float*)(ws + WS_S);
    float*   msr      = (float*)(ws + WS_MSR);
    float*   bias     = (float*)(ws + WS_BIAS);
    uint8_t* dirs     = (uint8_t*)(ws + WS_DIRS);
    int*     idx_map  = (int*)(ws + WS_IDX);
    int*     lens     = (int*)(ws + WS_LENS);
    float*   partials = (float*)(ws + WS_PART);

    hipLaunchKernelGGL(k_zero,    dim3(2048),      dim3(256), 0, stream, out);
    hipLaunchKernelGGL(k_prep,    dim3(3072),      dim3(256), 0, stream, logs_p, m_p, sarr, msr);
    hipLaunchKernelGGL(k_bias,    dim3(16),        dim3(256), 0, stream, logs_p, m_p, msr, bias);
    hipLaunchKernelGGL(k_len,     dim3(8),         dim3(256), 0, stream, tmask, smask, lens);
    hipLaunchKernelGGL(k_gemm,    dim3(8, 32, 8),  dim3(256), 0, stream, z_p, msr, sarr, bias, neg);
    hipLaunchKernelGGL(k_mas,     dim3(8),         dim3(256), 0, stream, neg, lens, dirs, idx_map);
    hipLaunchKernelGGL(k_scatter, dim3(64),        dim3(256), 0, stream, lens, idx_map, out);
    hipLaunchKernelGGL(k_gather,  dim3(3072),      dim3(256), 0, stream, z_p, m_p, logs_p, logs_q,
                       lens, idx_map, out, partials);
    hipLaunchKernelGGL(k_final,   dim3(1),         dim3(256), 0, stream, partials, lens, out);
}

// Round 8
// 694.842 us; speedup vs baseline: 2.0662x; 1.0618x over previous
//
#include <hip/hip_runtime.h>
#include <cstdint>
#include <cstddef>

// Problem shape (fixed by the reference): B=8, C=192, Tx=512, Ty=2048.
#define BB 8
#define CC 192
#define TXX 512
#define TYY 2048

#define NEG_INF (-1e9f)
#define HALF_LOG_2PI 0.9189385332046727f  // 0.5*log(2*pi)

// ---- output layout (floats, concatenated in return order) ----
// out0: MAS_path [B,1,Ty,Tx]  = 8*2048*512 = 8388608
// out1: m_p_a    [B,C,Ty]     = 3145728
// out2: logs_p_a [B,C,Ty]     = 3145728
// out3: loss_kl  scalar       = 1
// out4: duration [B,1,Tx]     = 4096
#define O1 8388608
#define O2 11534336
#define O3 14680064
#define O4 14680065

// ---- workspace layout (bytes). total ~39.1 MB ----
#define WS_NEG   0           // neg_cent fp32 [B,Ty,Tx]           33,554,432 B
#define WS_S     33554432    // s_p_sq_r [B,C,Tx]                  3,145,728 B
#define WS_MSR   36700160    // m_p * s  [B,C,Tx]                  3,145,728 B
#define WS_BIAS  39845888    // nc1+nc4  [B,Tx]                       16,384 B
#define WS_DIRS  39862272    // dir bits [B,Ty,64] bytes           1,048,576 B
#define WS_IDX   40910848    // idx_map  [B,Ty] int                   65,536 B
#define WS_LENS  40976384    // int text_len[8], spec_len[8]             64 B
#define WS_PART  40976448    // kl partials [3072] float              12,288 B

// ---------------------------------------------------------------------------
// Zero the path output region (mostly-zero one-hot) + duration.
__global__ void k_zero(float* __restrict__ out) {
    int64_t i = (int64_t)blockIdx.x * blockDim.x + threadIdx.x;
    const int64_t n4 = (int64_t)BB * TYY * TXX / 4;
    float4 z4 = make_float4(0.f, 0.f, 0.f, 0.f);
    float4* p4 = (float4*)out;
    for (int64_t k = i; k < n4; k += (int64_t)gridDim.x * blockDim.x) p4[k] = z4;
    if (i < BB * TXX) out[O4 + i] = 0.0f;
}

// s = exp(-2*logs_p), msr = m_p * s   (elementwise over [B,C,Tx])
__global__ void k_prep(const float* __restrict__ logs_p, const float* __restrict__ m_p,
                       float* __restrict__ s, float* __restrict__ msr) {
    int i = blockIdx.x * blockDim.x + threadIdx.x;  // exactly B*C*Tx threads
    float lp = logs_p[i], m = m_p[i];
    float sv = expf(-2.0f * lp);
    s[i] = sv;
    msr[i] = m * sv;
}

// bias[b,x] = sum_c( -0.5*log(2pi) - logs_p - 0.5*m_p*msr )   (nc1 + nc4)
__global__ void k_bias(const float* __restrict__ logs_p, const float* __restrict__ m_p,
                       const float* __restrict__ msr, float* __restrict__ bias) {
    int i = blockIdx.x * blockDim.x + threadIdx.x;  // B*Tx = 4096 threads
    int b = i >> 9, x = i & (TXX - 1);
    size_t base = (size_t)b * CC * TXX + x;
    const float* lpb = logs_p + base;
    const float* mb  = m_p + base;
    const float* msb = msr + base;
    float acc = 0.f;
#pragma unroll 8
    for (int c = 0; c < CC; ++c)
        acc += -HALF_LOG_2PI - lpb[(size_t)c * TXX] - 0.5f * mb[(size_t)c * TXX] * msb[(size_t)c * TXX];
    bias[i] = acc;
}

// text_len / spec_len per batch from the float masks.
__global__ void k_len(const float* __restrict__ tmask, const float* __restrict__ smask,
                      int* __restrict__ lens) {
    __shared__ float red[256];
    int b = blockIdx.x, tid = threadIdx.x;
    float ts = 0.f;
    for (int i = tid; i < TXX; i += 256) ts += tmask[b * TXX + i];
    red[tid] = ts; __syncthreads();
    for (int s = 128; s > 0; s >>= 1) { if (tid < s) red[tid] += red[tid + s]; __syncthreads(); }
    if (tid == 0) lens[b] = (int)(red[0] + 0.5f);
    __syncthreads();
    float ss = 0.f;
    for (int i = tid; i < TYY; i += 256) ss += smask[b * TYY + i];
    red[tid] = ss; __syncthreads();
    for (int s = 128; s > 0; s >>= 1) { if (tid < s) red[tid] += red[tid + s]; __syncthreads(); }
    if (tid == 0) lens[8 + b] = (int)(red[0] + 0.5f);
}

// neg_cent[b,t,x] = bias[b,x] + sum_c( z*msr + (-0.5*z^2)*s )
// fp32 LDS-tiled GEMM: 64x64 tile, BK=16, 256 threads, 4x4 per thread.
__global__ __launch_bounds__(256) void k_gemm(const float* __restrict__ z,
                                              const float* __restrict__ msr,
                                              const float* __restrict__ sarr,
                                              const float* __restrict__ bias,
                                              float* __restrict__ neg) {
    __shared__ float Zs[16][68], Ms[16][68], Ss[16][68];  // +4 pad
    int tid = threadIdx.x;
    int tx = tid & 15, ty = tid >> 4;          // cols (x), rows (t)
    int x0 = blockIdx.x * 64, t0 = blockIdx.y * 64, b = blockIdx.z;
    const float* zb = z    + (size_t)b * CC * TYY;
    const float* mb = msr  + (size_t)b * CC * TXX;
    const float* sb = sarr + (size_t)b * CC * TXX;
    int lr = tid >> 4, lc = (tid & 15) * 4;    // staging: row(k), col*4
    float acc[4][4] = {};
    for (int k0 = 0; k0 < CC; k0 += 16) {
        float4 zv = *(const float4*)(zb + (size_t)(k0 + lr) * TYY + t0 + lc);
        float4 mv = *(const float4*)(mb + (size_t)(k0 + lr) * TXX + x0 + lc);
        float4 sv = *(const float4*)(sb + (size_t)(k0 + lr) * TXX + x0 + lc);
        __syncthreads();
        *(float4*)&Zs[lr][lc] = zv;
        *(float4*)&Ms[lr][lc] = mv;
        *(float4*)&Ss[lr][lc] = sv;
        __syncthreads();
#pragma unroll
        for (int k = 0; k < 16; ++k) {
            float4 a4  = *(const float4*)&Zs[k][ty * 4];
            float4 bm4 = *(const float4*)&Ms[k][tx * 4];
            float4 bs4 = *(const float4*)&Ss[k][tx * 4];
            float av[4]  = {a4.x, a4.y, a4.z, a4.w};
            float bmv[4] = {bm4.x, bm4.y, bm4.z, bm4.w};
            float bsv[4] = {bs4.x, bs4.y, bs4.z, bs4.w};
#pragma unroll
            for (int i2 = 0; i2 < 4; ++i2) {
                float a2 = -0.5f * av[i2] * av[i2];
#pragma unroll
                for (int j = 0; j < 4; ++j)
                    acc[i2][j] += av[i2] * bmv[j] + a2 * bsv[j];
            }
        }
    }
    float4 b4 = *(const float4*)(bias + b * TXX + x0 + tx * 4);
    float bv[4] = {b4.x, b4.y, b4.z, b4.w};
#pragma unroll
    for (int i2 = 0; i2 < 4; ++i2) {
        int t = t0 + ty * 4 + i2;
        float4 o;
        o.x = acc[i2][0] + bv[0]; o.y = acc[i2][1] + bv[1];
        o.z = acc[i2][2] + bv[2]; o.w = acc[i2][3] + bv[3];
        *(float4*)(neg + ((size_t)b * TYY + t) * TXX + x0 + tx * 4) = o;
    }
}

// Monotonic alignment search, producer-consumer wave specialization.
// wave 0 = DP consumer (LDS-fed); waves 1..3 = feeders staging 8-row groups
// into a 4-slot LDS ring (sync: volatile LDS counters + threadfence_block).
// R7 post-mortem (456 us = 535 cyc/row): the consumer's critical path was
// dominated by ds_bpermute — __shfl_up per forward row (~120 cyc LDS
// latency, and its lgkmcnt wait also drained the next-row ds_read
// prefetches), and 4 __shfl broadcasts per backtrack step.
// R8: (a) forward boundary shift via DPP wave_shr:1 (ctrl 0x138, a VALU
// lane-shift CDNA kept from GFX9) — no LDS op on the row chain;
// (b) backtrack: idx is wave-uniform and j is the loop counter, so
// __builtin_amdgcn_readlane scalarizes the whole serial chain into SALU.
__global__ __launch_bounds__(256, 1) void k_mas(const float* __restrict__ neg,
                                                const int* __restrict__ lens,
                                                uint8_t* __restrict__ dirs,
                                                int* __restrict__ idx_map) {
    __shared__ float4 ring[4096];   // 4 slots x 8 rows x 128 float4 = 64 KB
    __shared__ int feed_done[3];
    __shared__ int cons_cnt;

    int b = blockIdx.x;
    int tid = threadIdx.x;
    int wave = tid >> 6, lane = tid & 63;
    const float* nc = neg + (size_t)b * TYY * TXX;
    uint8_t* db = dirs + (size_t)b * TYY * 64;

    if (tid == 0) { feed_done[0] = feed_done[1] = feed_done[2] = 0; cons_cnt = 0; }
    __syncthreads();

    if (wave != 0) {
        // ---- feeder ----
        int w = wave - 1;  // 0..2
        const float4* nc4 = (const float4*)nc;
        int cnt = 0;
        for (int g = w; g < TYY / 8; g += 3) {
            if (g >= 4) {
                while (*(volatile int*)&cons_cnt < g - 3) __builtin_amdgcn_s_sleep(1);
            }
            const float4* g4 = nc4 + (size_t)g * 1024;  // 8 rows x 128 float4
            float4 t[16];
#pragma unroll
            for (int r = 0; r < 8; ++r) {
                t[2 * r]     = g4[r * 128 + lane];
                t[2 * r + 1] = g4[r * 128 + 64 + lane];
            }
            float4* lb = ring + (size_t)(g & 3) * 1024;
            int p0 = (lane & 1) * 64 + (lane >> 1);        // pos of float4 #lane
            int p1 = p0 + 32;                              // pos of float4 #(64+lane)
#pragma unroll
            for (int r = 0; r < 8; ++r) {
                lb[r * 128 + p0] = t[2 * r];
                lb[r * 128 + p1] = t[2 * r + 1];
            }
            __threadfence_block();   // data visible before counter
            ++cnt;
            if (lane == 0) *(volatile int*)&feed_done[w] = cnt;
        }
        return;
    }

    // ---- consumer: forward DP ----
    int tlen = lens[b], slen = lens[8 + b];
    float v[8];
#pragma unroll
    for (int j = 0; j < 8; ++j) v[j] = NEG_INF;

    for (int g = 0; g < TYY / 8; ++g) {
        int f = g % 3, need = g / 3 + 1;
        while (*(volatile int*)&feed_done[f] < need) __builtin_amdgcn_s_sleep(1);
        __threadfence_block();
        const float4* lb = ring + (size_t)(g & 3) * 1024;
        float4 c0 = lb[lane], c1 = lb[64 + lane];
#pragma unroll
        for (int r = 0; r < 8; ++r) {
            float4 n0, n1;
            if (r < 7) { n0 = lb[(r + 1) * 128 + lane]; n1 = lb[(r + 1) * 128 + 64 + lane]; }
            int y = 8 * g + r;
            if (y == 0) {
                if (lane == 0) v[0] = c0.x;   // y==0: only x==0 gets its score
                db[lane] = 0;                 // dirs row 0 all-false
            } else {
                float sc[8] = {c0.x, c0.y, c0.z, c0.w, c1.x, c1.y, c1.z, c1.w};
                // boundary: left neighbor's v[7], via DPP wave_shr:1 (VALU,
                // no LDS). bound_ctrl=false + old=0: lane 0 gets 0, then
                // overridden with NEG_INF below.
                float pl = __int_as_float(__builtin_amdgcn_update_dpp(
                    0, __float_as_int(v[7]), 0x138, 0xF, 0xF, false));
                if (lane == 0) pl = NEG_INF;
                float nv[8];
                unsigned d = 0;
#pragma unroll
                for (int jj = 0; jj < 8; ++jj) {
                    float diag = (jj == 0) ? pl : v[jj - 1];
                    if (diag > v[jj]) d |= (1u << jj);
                    nv[jj] = sc[jj] + fmaxf(v[jj], diag);
                }
#pragma unroll
                for (int jj = 0; jj < 8; ++jj) v[jj] = nv[jj];
                db[(size_t)y * 64 + lane] = (uint8_t)d;
            }
            c0 = n0; c1 = n1;
        }
        __threadfence_block();   // LDS reads done before freeing the slot
        if (lane == 0) *(volatile int*)&cons_cnt = g + 1;
    }

    // ---- backtrack (scalarized serial chain) ----
    int idx = tlen - 1;
    int y0 = slen - 1;
    while (y0 >= 0) {
        int y = y0 - lane;
        int yy = (y < 0) ? 0 : y;
        // 4-word window [w0, w0+3] covers idx range for the whole slab
        // (idx decreases by at most 64 across 64 steps). idx is uniform at
        // slab entry -> w0 is uniform.
        int w0 = (idx >> 5) - 2;
        if (w0 < 0) w0 = 0;
        if (w0 > 12) w0 = 12;
        const uint32_t* rw = (const uint32_t*)(db + (size_t)yy * 64);
        uint32_t wa = rw[w0], wbv = rw[w0 + 1], wcv = rw[w0 + 2], wdv = rw[w0 + 3];
        int nsteps = (y0 + 1 < 64) ? y0 + 1 : 64;
        int cap = 0;
        for (int j = 0; j < nsteps; ++j) {
            if (lane == j) cap = idx;   // row y0-j emits one-hot at entering idx
            // row (y0-j)'s window lives in lane j; readlane -> SGPRs, the
            // whole per-step chain stays scalar.
            uint32_t s0 = (uint32_t)__builtin_amdgcn_readlane((int)wa,  j);
            uint32_t s1 = (uint32_t)__builtin_amdgcn_readlane((int)wbv, j);
            uint32_t s2 = (uint32_t)__builtin_amdgcn_readlane((int)wcv, j);
            uint32_t s3 = (uint32_t)__builtin_amdgcn_readlane((int)wdv, j);
            int wi = (idx >> 5) - w0;   // 0..3 guaranteed
            uint32_t lo = (wi & 1) ? s1 : s0;
            uint32_t hi = (wi & 1) ? s3 : s2;
            uint32_t word = (wi & 2) ? hi : lo;
            int bit = (int)((word >> (idx & 31)) & 1u);
            int yj = y0 - j;
            int move = (int)(idx != 0) & ((int)(idx == yj) | bit);
            idx -= move;
        }
        if (lane < nsteps) idx_map[b * TYY + y] = cap;
        y0 -= 64;
    }
}

// Scatter path one-hots + duration histogram from idx_map.
__global__ void k_scatter(const int* __restrict__ lens, const int* __restrict__ idx_map,
                          float* __restrict__ out) {
    int i = blockIdx.x * blockDim.x + threadIdx.x;  // B*Ty threads
    int b = i >> 11, y = i & (TYY - 1);
    if (y < lens[8 + b]) {
        int x = idx_map[i];
        out[(size_t)i * TXX + x] = 1.0f;
        atomicAdd(&out[O4 + b * TXX + x], 1.0f);
    }
}

// Gather m_p/logs_p onto spec frames via idx_map; fused KL partial sums.
__global__ __launch_bounds__(256) void k_gather(const float* __restrict__ z_p,
                                                const float* __restrict__ m_p,
                                                const float* __restrict__ logs_p,
                                                const float* __restrict__ logs_q,
                                                const int* __restrict__ lens,
                                                const int* __restrict__ idx_map,
                                                float* __restrict__ out,
                                                float* __restrict__ partials) {
    const int S = BB * CC * TYY / 4;  // 786432 stride, 4 elems/thread
    int base = blockIdx.x * 256 + threadIdx.x;
    float klsum = 0.f;
#pragma unroll
    for (int r = 0; r < 4; ++r) {
        int i = base + r * S;
        int t = i & (TYY - 1);
        int bc = i >> 11;      // b*C + c
        int b = bc / CC;
        float ma = 0.f, la = 0.f;
        if (t < lens[8 + b]) {
            int x = idx_map[b * TYY + t];
            size_t off = (size_t)bc * TXX + x;
            ma = m_p[off];
            la = logs_p[off];
            float zv = z_p[i], lq = logs_q[i];
            float dz = zv - ma;
            klsum += la - lq - 0.5f + 0.5f * dz * dz * expf(-2.0f * la);
        }
        out[O1 + i] = ma;
        out[O2 + i] = la;
    }
    for (int o = 32; o > 0; o >>= 1) klsum += __shfl_down(klsum, o);
    __shared__ float red[4];
    if ((threadIdx.x & 63) == 0) red[threadIdx.x >> 6] = klsum;
    __syncthreads();
    if (threadIdx.x == 0) partials[blockIdx.x] = red[0] + red[1] + red[2] + red[3];
}

__global__ void k_final(const float* __restrict__ partials, const int* __restrict__ lens,
                        float* __restrict__ out) {
    float s = 0.f;
    for (int i = threadIdx.x; i < 3072; i += 256) s += partials[i];
    for (int o = 32; o > 0; o >>= 1) s += __shfl_down(s, o);
    __shared__ float red[4];
    if ((threadIdx.x & 63) == 0) red[threadIdx.x >> 6] = s;
    __syncthreads();
    if (threadIdx.x == 0) {
        float tot = 0.f;
        for (int b = 0; b < 8; ++b) tot += (float)lens[8 + b];
        out[O3] = (red[0] + red[1] + red[2] + red[3]) / tot;
    }
}

extern "C" void kernel_launch(void* const* d_in, const int* in_sizes, int n_in,
                              void* d_out, int out_size, void* d_ws, size_t ws_size,
                              hipStream_t stream) {
    const float* z_p    = (const float*)d_in[0];
    const float* m_p    = (const float*)d_in[1];
    const float* logs_p = (const float*)d_in[2];
    const float* logs_q = (const float*)d_in[3];
    const float* tmask  = (const float*)d_in[4];
    const float* smask  = (const float*)d_in[5];
    float* out = (float*)d_out;
    char* ws = (char*)d_ws;

    float*   neg      = (float*)(ws + WS_NEG);
    float*   sarr     = (float*)(ws + WS_S);
    float*   msr      = (float*)(ws + WS_MSR);
    float*   bias     = (float*)(ws + WS_BIAS);
    uint8_t* dirs     = (uint8_t*)(ws + WS_DIRS);
    int*     idx_map  = (int*)(ws + WS_IDX);
    int*     lens     = (int*)(ws + WS_LENS);
    float*   partials = (float*)(ws + WS_PART);

    hipLaunchKernelGGL(k_zero,    dim3(2048),      dim3(256), 0, stream, out);
    hipLaunchKernelGGL(k_prep,    dim3(3072),      dim3(256), 0, stream, logs_p, m_p, sarr, msr);
    hipLaunchKernelGGL(k_bias,    dim3(16),        dim3(256), 0, stream, logs_p, m_p, msr, bias);
    hipLaunchKernelGGL(k_len,     dim3(8),         dim3(256), 0, stream, tmask, smask, lens);
    hipLaunchKernelGGL(k_gemm,    dim3(8, 32, 8),  dim3(256), 0, stream, z_p, msr, sarr, bias, neg);
    hipLaunchKernelGGL(k_mas,     dim3(8),         dim3(256), 0, stream, neg, lens, dirs, idx_map);
    hipLaunchKernelGGL(k_scatter, dim3(64),        dim3(256), 0, stream, lens, idx_map, out);
    hipLaunchKernelGGL(k_gather,  dim3(3072),      dim3(256), 0, stream, z_p, m_p, logs_p, logs_q,
                       lens, idx_map, out, partials);
    hipLaunchKernelGGL(k_final,   dim3(1),         dim3(256), 0, stream, partials, lens, out);
}